// Round 14
// baseline (121.921 us; speedup 1.0000x reference)
//
#include <hip/hip_runtime.h>

static constexpr int OHW = 12, NSP = 144;

typedef float f2 __attribute__((ext_vector_type(2)));

// ---------------------------------------------------------------------------
// build_T: gather x (4,256,14,14) -> T[n][k][i], n = b*144+oh*12+ow,
// k = (kh*3+kw)*32 + ic, i in [0,8). One float4 (4 consecutive i) per thread.
// ---------------------------------------------------------------------------
__global__ void build_T(const float* __restrict__ x, float4* __restrict__ T4) {
    const int g = blockIdx.x * 256 + threadIdx.x;   // [0, 576*576)
    const int n = g / 576;                          // 576 float4 per n
    const int q = g - n * 576;
    const int r = q << 2;                           // float offset in row
    const int k = r >> 3;
    const int i0 = r & 7;                           // 0 or 4
    const int ic = k & 31;
    const int kk = k >> 5;
    const int kh = kk / 3, kw = kk - kh * 3;
    const int b = n / NSP;
    const int rm = n - b * NSP;
    const int oh = rm / OHW, ow = rm - oh * OHW;
    const float* xp = x + (size_t)(b * 256 + ic * 8 + i0) * 196
                        + (oh + kh) * 14 + (ow + kw);
    float4 v;
    v.x = xp[0];
    v.y = xp[196];
    v.z = xp[392];
    v.w = xp[588];
    T4[g] = v;
}

// ---- packed fp32 helpers: ONLY vanilla forms, no op_sel (R13 lesson: the
// op_sel broadcast encoding on 64-bit VOP3P mis-selected halves -> 1.2e-2
// absmax fail). Default packed semantics are unambiguous. ------------------
__device__ __forceinline__ f2 lo2(const float4& v) { return f2{v.x, v.y}; }
__device__ __forceinline__ f2 hi2(const float4& v) { return f2{v.z, v.w}; }

__device__ __forceinline__ f2 pk_mul(f2 a, f2 b) {
    f2 d; asm("v_pk_mul_f32 %0, %1, %2" : "=v"(d) : "v"(a), "v"(b)); return d;
}
__device__ __forceinline__ f2 pk_fma(f2 a, f2 b, f2 c) {
    f2 d; asm("v_pk_fma_f32 %0, %1, %2, %3"
              : "=v"(d) : "v"(a), "v"(b), "v"(c)); return d;
}
__device__ __forceinline__ f2 pk_add(f2 a, f2 b) {
    f2 d; asm("v_pk_add_f32 %0, %1, %2" : "=v"(d) : "v"(a), "v"(b)); return d;
}

__device__ __forceinline__ void fma4(float4& a, float s, const float4& w) {
    a.x = fmaf(s, w.x, a.x);
    a.y = fmaf(s, w.y, a.y);
    a.z = fmaf(s, w.z, a.z);
    a.w = fmaf(s, w.w, a.w);
}

// ---- all-VALU reduce helpers (R7 + R10, both verified passing) ------------
template <int CTRL>
__device__ __forceinline__ float dppmov(float v) {
    return __int_as_float(__builtin_amdgcn_update_dpp(
        0, __float_as_int(v), CTRL, 0xF, 0xF, true));
}

__device__ __forceinline__ float cred(float v) {       // sum over c-quad
    v += dppmov<0xB1>(v);   // quad_perm [1,0,3,2]
    v += dppmov<0x4E>(v);   // quad_perm [2,3,0,1]
    return v;
}

__device__ __forceinline__ float kred(float v) {       // sum over 16 kgp
    v += dppmov<0x124>(v);  // row_ror:4
    v += dppmov<0x128>(v);  // row_ror:8
#if __has_builtin(__builtin_amdgcn_permlane16_swap)
    {
        auto p = __builtin_amdgcn_permlane16_swap(__float_as_int(v),
                                                  __float_as_int(v),
                                                  false, false);
        v = __int_as_float(p[0]) + __int_as_float(p[1]);
    }
#else
    v += __int_as_float(__builtin_amdgcn_ds_swizzle(__float_as_int(v), 0x401F));
#endif
#if __has_builtin(__builtin_amdgcn_permlane32_swap)
    {
        auto q = __builtin_amdgcn_permlane32_swap(__float_as_int(v),
                                                  __float_as_int(v),
                                                  false, false);
        v = __int_as_float(q[0]) + __int_as_float(q[1]);
    }
#else
    v += __shfl_xor(v, 32);
#endif
    return v;
}

__device__ __forceinline__ void kred4(float4& v) {
    v.x = kred(v.x); v.y = kred(v.y); v.z = kred(v.z); v.w = kred(v.w);
}

__device__ __forceinline__ float dot4(const float4& a, const float4& b) {
    return a.x * b.x + a.y * b.y + a.z * b.z + a.w * b.w;
}

__device__ __forceinline__ float4 squash_vq(const float4& svU, float S) {
    const float invS = __frcp_rn(S);
    float4 s;
    s.x = svU.x * invS; s.y = svU.y * invS;
    s.z = svU.z * invS; s.w = svU.w * invS;
    float sq = dot4(s, s);
    sq = cred(sq);
    const float scale = __fsqrt_rn(sq) / (1.0f + sq);
    s.x *= scale; s.y *= scale; s.z *= scale; s.w *= scale;
    return s;
}

// One k-slab for EIGHT n's. Packed along the REDUCTION dim: per c-component
// acc pair accumulates {even-i, odd-i} partial products; w-pairs
// {w[2p].c, w[2p+1].c} are slab-invariant (packed once, amortized over 8 n).
// t-pairs are free (lo2/hi2 of the dwordx4 loads). 16 pk_fma + 4 adds per nn
// vs 32 scalar FMA. Reassociation only (even/odd chains + final add).
__device__ __forceinline__ void do_j8(const float4* __restrict__ T4,
                                      const float4* __restrict__ W4,
                                      float4* __restrict__ Pl,
                                      int o, int nbase, int k, int cg,
                                      int g_local, int lane) {
    float4 w[8];
    const float4* wp = W4 + (size_t)(o * 288 + k) * 32 + cg;
    #pragma unroll
    for (int i = 0; i < 8; ++i) w[i] = wp[i * 4];

    f2 wpk[4][4];                       // [i-pair p][c]
    #pragma unroll
    for (int p = 0; p < 4; ++p) {
        wpk[p][0] = f2{w[2 * p].x, w[2 * p + 1].x};
        wpk[p][1] = f2{w[2 * p].y, w[2 * p + 1].y};
        wpk[p][2] = f2{w[2 * p].z, w[2 * p + 1].z};
        wpk[p][3] = f2{w[2 * p].w, w[2 * p + 1].w};
    }

    #pragma unroll
    for (int nn = 0; nn < 8; ++nn) {
        const float4* tp = T4 + (size_t)(nbase + nn) * 576 + k * 2;
        const float4 t0 = tp[0];
        const float4 t1 = tp[1];
        f2 tpk[4];
        tpk[0] = lo2(t0); tpk[1] = hi2(t0);
        tpk[2] = lo2(t1); tpk[3] = hi2(t1);
        f2 acc0 = {0.f, 0.f}, acc1 = {0.f, 0.f};
        f2 acc2 = {0.f, 0.f}, acc3 = {0.f, 0.f};
        #pragma unroll
        for (int p = 0; p < 4; ++p) {
            acc0 = pk_fma(tpk[p], wpk[p][0], acc0);
            acc1 = pk_fma(tpk[p], wpk[p][1], acc1);
            acc2 = pk_fma(tpk[p], wpk[p][2], acc2);
            acc3 = pk_fma(tpk[p], wpk[p][3], acc3);
        }
        Pl[nn * 512 + g_local * 64 + lane] =
            make_float4(acc0.x + acc0.y, acc1.x + acc1.y,
                        acc2.x + acc2.y, acc3.x + acc3.y);
    }
}

// ---------------------------------------------------------------------------
// caps_main: R12 structure (best passing: 65.5 us, VALU-issue-bound at 57.5%
// busy) + packed-fp32 math WITHOUT op_sel. Block = (o, 8 n's), 512 threads,
// wave = n in phase 2. Occupancy 16 waves/CU (128 unified regs/wave, the
// unique non-spilling budget per R2-R11). LDS = 8n x 8slab x 64 f4 = 64 KB.
// Phase 2: it-0 via pk_add, dots via pk_mul/pk_fma + horizontal add;
// sv/S accumulation scalar (needs broadcast -> kept off the risky path).
// ---------------------------------------------------------------------------
__global__ __launch_bounds__(512, 4)
void caps_main(const float4* __restrict__ T4, const float4* __restrict__ W4,
               float* __restrict__ out) {
    __shared__ float4 Pl[8 * 8 * 64];   // 65,536 B
    const int tid = threadIdx.x;
    const int o = blockIdx.y;
    const int nbase = blockIdx.x * 8;
    const int cg = tid & 3;
    const int wv = tid >> 6;            // [0,8)
    const int lane = tid & 63;
    const int kg16 = lane >> 2;         // [0,16)

    float4 P[18];

    // ---- phase 1, chunk 0: slabs 0,1 on waves 0,1 ----
    if (wv < 2)
        do_j8(T4, W4, Pl, o, nbase, kg16 + 16 * wv, cg, wv, lane);
    __syncthreads();
    P[0] = Pl[wv * 512 + lane];
    P[1] = Pl[wv * 512 + 64 + lane];
    __syncthreads();

    // ---- phase 1, chunk 1: slabs 2..9, wave w -> slab 2+w ----
    do_j8(T4, W4, Pl, o, nbase, kg16 + 16 * (2 + wv), cg, wv, lane);
    __syncthreads();
    #pragma unroll
    for (int j = 0; j < 8; ++j)
        P[2 + j] = Pl[wv * 512 + j * 64 + lane];
    __syncthreads();

    // ---- phase 1, chunk 2: slabs 10..17, wave w -> slab 10+w ----
    do_j8(T4, W4, Pl, o, nbase, kg16 + 16 * (10 + wv), cg, wv, lane);
    __syncthreads();
    #pragma unroll
    for (int j = 0; j < 8; ++j)
        P[10 + j] = Pl[wv * 512 + j * 64 + lane];

    // ---- phase 2: dynamic routing, wave = n (= nbase + wv), fused passes --
    // it 0: uniform probs (packed adds, same per-jj order)
    f2 svLo = {0.f, 0.f}, svHi = {0.f, 0.f};
    #pragma unroll
    for (int jj = 0; jj < 18; ++jj) {
        svLo = pk_add(svLo, lo2(P[jj]));
        svHi = pk_add(svHi, hi2(P[jj]));
    }
    float4 sv = make_float4(svLo.x, svLo.y, svHi.x, svHi.y);
    kred4(sv);
    float4 vq = squash_vq(sv, 288.0f);

    // pass 1: lj = <P,vq0>_c ; sv = sum exp(lj)*P ; S = sum exp(lj)
    float lj[18];
    float S = 0.f;
    sv = make_float4(0.f, 0.f, 0.f, 0.f);
    f2 vqLo = lo2(vq), vqHi = hi2(vq);
    #pragma unroll
    for (int jj = 0; jj < 18; ++jj) {
        f2 m = pk_mul(lo2(P[jj]), vqLo);
        m = pk_fma(hi2(P[jj]), vqHi, m);
        const float d = cred(m.x + m.y);
        lj[jj] = d;
        const float e = __expf(d);     // |lj| small; no max needed
        S += e;
        fma4(sv, e, P[jj]);
    }
    kred4(sv);
    S = kred(S);
    vq = squash_vq(sv, S);

    // pass 2: logits = lj + <P,vq1>_c ; final sv/S ; squash
    S = 0.f;
    sv = make_float4(0.f, 0.f, 0.f, 0.f);
    vqLo = lo2(vq); vqHi = hi2(vq);
    #pragma unroll
    for (int jj = 0; jj < 18; ++jj) {
        f2 m = pk_mul(lo2(P[jj]), vqLo);
        m = pk_fma(hi2(P[jj]), vqHi, m);
        const float d = cred(m.x + m.y);
        const float e = __expf(lj[jj] + d);
        S += e;
        fma4(sv, e, P[jj]);
    }
    kred4(sv);
    S = kred(S);
    vq = squash_vq(sv, S);

    // ---- store: lanes kgp==0 write their c-quad ----
    if ((lane >> 2) == 0) {
        const int n = nbase + wv;
        const int b = n / NSP;
        const int rm = n - b * NSP;
        float* op = out + (size_t)(b * 512 + o * 16 + cg * 4) * NSP + rm;
        op[0 * NSP] = vq.x;
        op[1 * NSP] = vq.y;
        op[2 * NSP] = vq.z;
        op[3 * NSP] = vq.w;
    }
}

extern "C" void kernel_launch(void* const* d_in, const int* in_sizes, int n_in,
                              void* d_out, int out_size, void* d_ws, size_t ws_size,
                              hipStream_t stream) {
    const float* x  = (const float*)d_in[0];   // (4, 256, 14, 14)
    const float* wt = (const float*)d_in[1];   // (32, 288, 8, 16)
    float* out = (float*)d_out;                // (4, 512, 12, 12)
    float4* T4 = (float4*)d_ws;                // 576*2304 floats = 5.3 MB

    build_T<<<dim3(576 * 576 / 256), 256, 0, stream>>>(x, T4);
    caps_main<<<dim3(72, 32), 512, 0, stream>>>(T4, (const float4*)wt, out);
}

// Round 15
// 118.740 us; speedup vs baseline: 1.0268x; 1.0268x over previous
//
#include <hip/hip_runtime.h>

static constexpr int OHW = 12, NSP = 144;

typedef float f2 __attribute__((ext_vector_type(2)));

// ---------------------------------------------------------------------------
// build_T: gather x (4,256,14,14) -> T[n][k][i], n = b*144+oh*12+ow,
// k = (kh*3+kw)*32 + ic, i in [0,8). One float4 (4 consecutive i) per thread.
// ---------------------------------------------------------------------------
__global__ void build_T(const float* __restrict__ x, float4* __restrict__ T4) {
    const int g = blockIdx.x * 256 + threadIdx.x;   // [0, 576*576)
    const int n = g / 576;                          // 576 float4 per n
    const int q = g - n * 576;
    const int r = q << 2;                           // float offset in row
    const int k = r >> 3;
    const int i0 = r & 7;                           // 0 or 4
    const int ic = k & 31;
    const int kk = k >> 5;
    const int kh = kk / 3, kw = kk - kh * 3;
    const int b = n / NSP;
    const int rm = n - b * NSP;
    const int oh = rm / OHW, ow = rm - oh * OHW;
    const float* xp = x + (size_t)(b * 256 + ic * 8 + i0) * 196
                        + (oh + kh) * 14 + (ow + kw);
    float4 v;
    v.x = xp[0];
    v.y = xp[196];
    v.z = xp[392];
    v.w = xp[588];
    T4[g] = v;
}

// ---- packed fp32 helpers (vanilla VOP3P only; R13 banned op_sel) ----------
__device__ __forceinline__ f2 lo2(const float4& v) { return f2{v.x, v.y}; }
__device__ __forceinline__ f2 hi2(const float4& v) { return f2{v.z, v.w}; }

__device__ __forceinline__ f2 pk_mul(f2 a, f2 b) {
    f2 d; asm("v_pk_mul_f32 %0, %1, %2" : "=v"(d) : "v"(a), "v"(b)); return d;
}
__device__ __forceinline__ f2 pk_fma(f2 a, f2 b, f2 c) {
    f2 d; asm("v_pk_fma_f32 %0, %1, %2, %3"
              : "=v"(d) : "v"(a), "v"(b), "v"(c)); return d;
}
__device__ __forceinline__ f2 pk_add(f2 a, f2 b) {
    f2 d; asm("v_pk_add_f32 %0, %1, %2" : "=v"(d) : "v"(a), "v"(b)); return d;
}

__device__ __forceinline__ void fma4(float4& a, float s, const float4& w) {
    a.x = fmaf(s, w.x, a.x);
    a.y = fmaf(s, w.y, a.y);
    a.z = fmaf(s, w.z, a.z);
    a.w = fmaf(s, w.w, a.w);
}

// ---- all-VALU reduce helpers (R7 + R10, verified) -------------------------
template <int CTRL>
__device__ __forceinline__ float dppmov(float v) {
    return __int_as_float(__builtin_amdgcn_update_dpp(
        0, __float_as_int(v), CTRL, 0xF, 0xF, true));
}

__device__ __forceinline__ float cred(float v) {       // sum over c-quad
    v += dppmov<0xB1>(v);   // quad_perm [1,0,3,2]
    v += dppmov<0x4E>(v);   // quad_perm [2,3,0,1]
    return v;
}

__device__ __forceinline__ float kred(float v) {       // sum over 16 kgp
    v += dppmov<0x124>(v);  // row_ror:4
    v += dppmov<0x128>(v);  // row_ror:8
#if __has_builtin(__builtin_amdgcn_permlane16_swap)
    {
        auto p = __builtin_amdgcn_permlane16_swap(__float_as_int(v),
                                                  __float_as_int(v),
                                                  false, false);
        v = __int_as_float(p[0]) + __int_as_float(p[1]);
    }
#else
    v += __int_as_float(__builtin_amdgcn_ds_swizzle(__float_as_int(v), 0x401F));
#endif
#if __has_builtin(__builtin_amdgcn_permlane32_swap)
    {
        auto q = __builtin_amdgcn_permlane32_swap(__float_as_int(v),
                                                  __float_as_int(v),
                                                  false, false);
        v = __int_as_float(q[0]) + __int_as_float(q[1]);
    }
#else
    v += __shfl_xor(v, 32);
#endif
    return v;
}

__device__ __forceinline__ void kred4(float4& v) {
    v.x = kred(v.x); v.y = kred(v.y); v.z = kred(v.z); v.w = kred(v.w);
}

__device__ __forceinline__ float dot4(const float4& a, const float4& b) {
    return a.x * b.x + a.y * b.y + a.z * b.z + a.w * b.w;
}

__device__ __forceinline__ float4 squash_vq(const float4& svU, float S) {
    const float invS = __frcp_rn(S);
    float4 s;
    s.x = svU.x * invS; s.y = svU.y * invS;
    s.z = svU.z * invS; s.w = svU.w * invS;
    float sq = dot4(s, s);
    sq = cred(sq);
    const float scale = __fsqrt_rn(sq) / (1.0f + sq);
    s.x *= scale; s.y *= scale; s.z *= scale; s.w *= scale;
    return s;
}

// One k-slab for EIGHT n's (16 k x 4 c x 8 n): load w[8] ONCE, 8x(2 T-loads +
// 32 scalar FMA). R12's scalar form -- R14 showed packing this inner loop
// (wpk construction + horizontal adds) is a net loss vs plain fma4.
__device__ __forceinline__ void do_j8(const float4* __restrict__ T4,
                                      const float4* __restrict__ W4,
                                      float4* __restrict__ Pl,
                                      int o, int nbase, int k, int cg,
                                      int g_local, int lane) {
    float4 w[8];
    const float4* wp = W4 + (size_t)(o * 288 + k) * 32 + cg;
    #pragma unroll
    for (int i = 0; i < 8; ++i) w[i] = wp[i * 4];
    #pragma unroll
    for (int nn = 0; nn < 8; ++nn) {
        const float4* tp = T4 + (size_t)(nbase + nn) * 576 + k * 2;
        const float4 t0 = tp[0];
        const float4 t1 = tp[1];
        float4 a = make_float4(0.f, 0.f, 0.f, 0.f);
        fma4(a, t0.x, w[0]); fma4(a, t0.y, w[1]);
        fma4(a, t0.z, w[2]); fma4(a, t0.w, w[3]);
        fma4(a, t1.x, w[4]); fma4(a, t1.y, w[5]);
        fma4(a, t1.z, w[6]); fma4(a, t1.w, w[7]);
        Pl[nn * 512 + g_local * 64 + lane] = a;
    }
}

// ---------------------------------------------------------------------------
// caps_main: best-of merge. R12 phase 1 (scalar do_j8, best measured 65.5us)
// + R14 phase 2 (packed it-0/dots, passed at absmax 1.22e-4; packing there
// is free since P's lo/hi pairs are register pairs). Block = (o, 8 n's),
// 512 threads, wave = n in phase 2. Occupancy 16 waves/CU -- register-walled
// at 128 unified regs/wave (R2-R11: every tighter budget spills, every
// topology that shrinks P-state loses to barriers). LDS = 64 KB.
// ---------------------------------------------------------------------------
__global__ __launch_bounds__(512, 4)
void caps_main(const float4* __restrict__ T4, const float4* __restrict__ W4,
               float* __restrict__ out) {
    __shared__ float4 Pl[8 * 8 * 64];   // 65,536 B
    const int tid = threadIdx.x;
    const int o = blockIdx.y;
    const int nbase = blockIdx.x * 8;
    const int cg = tid & 3;
    const int wv = tid >> 6;            // [0,8)
    const int lane = tid & 63;
    const int kg16 = lane >> 2;         // [0,16)

    float4 P[18];

    // ---- phase 1, chunk 0: slabs 0,1 on waves 0,1 ----
    if (wv < 2)
        do_j8(T4, W4, Pl, o, nbase, kg16 + 16 * wv, cg, wv, lane);
    __syncthreads();
    P[0] = Pl[wv * 512 + lane];
    P[1] = Pl[wv * 512 + 64 + lane];
    __syncthreads();

    // ---- phase 1, chunk 1: slabs 2..9, wave w -> slab 2+w ----
    do_j8(T4, W4, Pl, o, nbase, kg16 + 16 * (2 + wv), cg, wv, lane);
    __syncthreads();
    #pragma unroll
    for (int j = 0; j < 8; ++j)
        P[2 + j] = Pl[wv * 512 + j * 64 + lane];
    __syncthreads();

    // ---- phase 1, chunk 2: slabs 10..17, wave w -> slab 10+w ----
    do_j8(T4, W4, Pl, o, nbase, kg16 + 16 * (10 + wv), cg, wv, lane);
    __syncthreads();
    #pragma unroll
    for (int j = 0; j < 8; ++j)
        P[10 + j] = Pl[wv * 512 + j * 64 + lane];

    // ---- phase 2: dynamic routing, wave = n (= nbase + wv), fused passes --
    // it 0: uniform probs (packed adds, same per-jj order)
    f2 svLo = {0.f, 0.f}, svHi = {0.f, 0.f};
    #pragma unroll
    for (int jj = 0; jj < 18; ++jj) {
        svLo = pk_add(svLo, lo2(P[jj]));
        svHi = pk_add(svHi, hi2(P[jj]));
    }
    float4 sv = make_float4(svLo.x, svLo.y, svHi.x, svHi.y);
    kred4(sv);
    float4 vq = squash_vq(sv, 288.0f);

    // pass 1: lj = <P,vq0>_c ; sv = sum exp(lj)*P ; S = sum exp(lj)
    float lj[18];
    float S = 0.f;
    sv = make_float4(0.f, 0.f, 0.f, 0.f);
    f2 vqLo = lo2(vq), vqHi = hi2(vq);
    #pragma unroll
    for (int jj = 0; jj < 18; ++jj) {
        f2 m = pk_mul(lo2(P[jj]), vqLo);
        m = pk_fma(hi2(P[jj]), vqHi, m);
        const float d = cred(m.x + m.y);
        lj[jj] = d;
        const float e = __expf(d);     // |lj| small; no max needed
        S += e;
        fma4(sv, e, P[jj]);
    }
    kred4(sv);
    S = kred(S);
    vq = squash_vq(sv, S);

    // pass 2: logits = lj + <P,vq1>_c ; final sv/S ; squash
    S = 0.f;
    sv = make_float4(0.f, 0.f, 0.f, 0.f);
    vqLo = lo2(vq); vqHi = hi2(vq);
    #pragma unroll
    for (int jj = 0; jj < 18; ++jj) {
        f2 m = pk_mul(lo2(P[jj]), vqLo);
        m = pk_fma(hi2(P[jj]), vqHi, m);
        const float d = cred(m.x + m.y);
        const float e = __expf(lj[jj] + d);
        S += e;
        fma4(sv, e, P[jj]);
    }
    kred4(sv);
    S = kred(S);
    vq = squash_vq(sv, S);

    // ---- store: lanes kgp==0 write their c-quad ----
    if ((lane >> 2) == 0) {
        const int n = nbase + wv;
        const int b = n / NSP;
        const int rm = n - b * NSP;
        float* op = out + (size_t)(b * 512 + o * 16 + cg * 4) * NSP + rm;
        op[0 * NSP] = vq.x;
        op[1 * NSP] = vq.y;
        op[2 * NSP] = vq.z;
        op[3 * NSP] = vq.w;
    }
}

extern "C" void kernel_launch(void* const* d_in, const int* in_sizes, int n_in,
                              void* d_out, int out_size, void* d_ws, size_t ws_size,
                              hipStream_t stream) {
    const float* x  = (const float*)d_in[0];   // (4, 256, 14, 14)
    const float* wt = (const float*)d_in[1];   // (32, 288, 8, 16)
    float* out = (float*)d_out;                // (4, 512, 12, 12)
    float4* T4 = (float4*)d_ws;                // 576*2304 floats = 5.3 MB

    build_T<<<dim3(576 * 576 / 256), 256, 0, stream>>>(x, T4);
    caps_main<<<dim3(72, 32), 512, 0, stream>>>(T4, (const float4*)wt, out);
}